// Round 4
// baseline (28435.483 us; speedup 1.0000x reference)
//
#include <hip/hip_runtime.h>
#include <hip/hip_bf16.h>

// ---------------------------------------------------------------------------
// Decoder: 200-step attention LSTM decoder.
//   prep_kernel : convert/permute weights & KV to bf16 (unchanged layout)
//   k1_gemm     : X1pre[t,n,2048] = emb[text] @ Wih1_emb^T + (b_ih1+b_hh1)  (MFMA)
//   loop_kernel : v4 — BARRIER-FREE per-row persistent kernel.
//                 The recurrence is independent per batch row n: h1/c1/h2/c2/ctx
//                 of row n depend only on row n's history, and attention reads
//                 K/V[:, n, :] only. One WG (512 thr) owns one row for all 200
//                 steps: zero grid barriers, zero atomics (the 3x200 grid
//                 barriers at ~37us each were the entire previous runtime).
//                 GEMVs via MFMA with x broadcast across M-rows; weights
//                 streamed from L2 (3.3 MB, L2-resident per XCD); K staged in
//                 LDS once; c-states in registers. Replay-safe: no cross-launch
//                 global state.
//   k4_gemm     : out[n,l,:] = [h2|ctx] @ W_out^T + b_out                    (MFMA)
// Workspace requirement: ~93.3 MB (unchanged).
// ---------------------------------------------------------------------------

typedef __bf16 bf16;
typedef __attribute__((ext_vector_type(8))) __bf16 bf16x8;
typedef __attribute__((ext_vector_type(4))) float f32x4;
typedef unsigned int uint;

#define MFMA(a, b, c) __builtin_amdgcn_mfma_f32_16x16x32_bf16((a), (b), (c), 0, 0, 0)

// ---- workspace byte offsets (all 256-aligned) ----
#define O_X1     0UL          // X1pre bf16 [200][64][2048]          52,428,800
#define O_EMBB   52428800UL   // emb bf16 [8000][512]                 8,192,000
#define O_WEMBP  60620800UL   // Wih1 embed-part, permuted rows, bf16 [2048][512]
#define O_WZ1    62717952UL   // [Wih1_ctx | Whh1] permuted, bf16 [2048][640]
#define O_WZ2    65339392UL   // [Whh2 | Wih2] permuted, bf16 [512][640]
#define O_B1P    65994752UL   // b_ih1+b_hh1 permuted fp32 [2048]
#define O_B2P    66002944UL   // b_ih2+b_hh2 permuted fp32 [512]
#define O_WOUTB  66004992UL   // W_out bf16 [8000][256]
#define O_KEYB   70100992UL   // key bf16 [500][64][128]
#define O_VALB   78292992UL   // values bf16 [500][64][128]
#define O_H1     86484992UL   // (unused by v4 loop; kept for layout stability)
#define O_H2     86616064UL   // (unused)
#define O_PART   86648832UL   // (unused)
#define O_H2CTX  86718464UL   // [h2|ctx] bf16 [200][64][256]
#define O_BAR    93272064UL   // (unused)

// ---- v4 loop kernel LDS offsets (bytes, all 16B-aligned) ----
#define LK_K    0        // K row-n: [500][66 uints] (pitch 264B) = 132,000 B
#define LK_X1   132096   // x1 = [ctx(128) | h1(512)] bf16        = 1,280 B
#define LK_X2   133376   // x2 = [h2(128)  | h1(512)] bf16        = 1,280 B
#define LK_Z1   134656   // z1 f32 [2048]                         = 8,192 B
#define LK_Z2   142848   // z2 f32 [512]                          = 2,048 B
#define LK_H2F  144896   // h2 f32 [128]                          = 512 B
#define LK_P    145408   // softmax probs f32 [512]               = 2,048 B
#define LK_CP   147456   // ctx partials f32 [16][128]            = 8,192 B
#define LK_RED  155648   // wave reduction scratch f32 [16]       = 64 B
#define LDS2_TOTAL 155712

__device__ inline float sigf(float x) { return 1.f / (1.f + __expf(-x)); }
__device__ inline float tanhf_(float x) { float e = __expf(2.f * x); return 1.f - 2.f / (e + 1.f); }
__device__ inline float bflo(uint u) { union { uint u; float f; } c; c.u = u << 16; return c.f; }
__device__ inline float bfhi(uint u) { union { uint u; float f; } c; c.u = u & 0xffff0000u; return c.f; }
__device__ inline float bfu(unsigned short u) { union { uint u; float f; } c; c.u = ((uint)u) << 16; return c.f; }
__device__ inline float wred_max(float v) {
#pragma unroll
  for (int m = 32; m; m >>= 1) v = fmaxf(v, __shfl_xor(v, m, 64));
  return v;
}
__device__ inline float wred_sum(float v) {
#pragma unroll
  for (int m = 32; m; m >>= 1) v += __shfl_xor(v, m, 64);
  return v;
}

// =============================== prep ======================================
__global__ __launch_bounds__(256) void prep_kernel(
    const float* __restrict__ key, const float* __restrict__ values,
    const float* __restrict__ emb, const float* __restrict__ Wih1,
    const float* __restrict__ Whh1, const float* __restrict__ bih1,
    const float* __restrict__ bhh1, const float* __restrict__ Wih2,
    const float* __restrict__ Whh2, const float* __restrict__ bih2,
    const float* __restrict__ bhh2, const float* __restrict__ Wout,
    char* __restrict__ ws) {
  long g = (long)blockIdx.x * 256 + threadIdx.x;
  long str = (long)gridDim.x * 256;
  bf16* embB = (bf16*)(ws + O_EMBB);
  bf16* WembP = (bf16*)(ws + O_WEMBP);
  bf16* Wz1p = (bf16*)(ws + O_WZ1);
  bf16* Wz2p = (bf16*)(ws + O_WZ2);
  float* b1p = (float*)(ws + O_B1P);
  float* b2p = (float*)(ws + O_B2P);
  bf16* WoutB = (bf16*)(ws + O_WOUTB);
  bf16* keyB = (bf16*)(ws + O_KEYB);
  bf16* valB = (bf16*)(ws + O_VALB);

  for (long i = g; i < 8000L * 512; i += str) embB[i] = (bf16)emb[i];
  for (long i = g; i < 2048L * 512; i += str) {
    long gg = i >> 9, k = i & 511;
    long pg = (gg & 3) * 512 + (gg >> 2);
    WembP[i] = (bf16)Wih1[pg * 640 + k];
  }
  for (long i = g; i < 2048L * 640; i += str) {
    long gg = i / 640, k = i - gg * 640;
    long pg = (gg & 3) * 512 + (gg >> 2);
    float v = (k < 128) ? Wih1[pg * 640 + 512 + k] : Whh1[pg * 512 + (k - 128)];
    Wz1p[i] = (bf16)v;
  }
  for (long i = g; i < 512L * 640; i += str) {
    long gg = i / 640, k = i - gg * 640;
    long pg = (gg & 3) * 128 + (gg >> 2);
    float v = (k < 128) ? Whh2[pg * 128 + k] : Wih2[pg * 512 + (k - 128)];
    Wz2p[i] = (bf16)v;
  }
  for (long i = g; i < 2048; i += str) {
    long pg = (i & 3) * 512 + (i >> 2);
    b1p[i] = bih1[pg] + bhh1[pg];
  }
  for (long i = g; i < 512; i += str) {
    long pg = (i & 3) * 128 + (i >> 2);
    b2p[i] = bih2[pg] + bhh2[pg];
  }
  for (long i = g; i < 8000L * 256; i += str) WoutB[i] = (bf16)Wout[i];
  for (long i = g; i < 500L * 64 * 128; i += str) {
    keyB[i] = (bf16)key[i];
    valB[i] = (bf16)values[i];
  }
}

// ========================= K1: embedding pre-GEMM ==========================
// X1pre[m=t*64+n][g~] = sum_k emb[text[n][t]][k] * WembP[g~][k] + b1p[g~]
__global__ __launch_bounds__(256) void k1_gemm(const int* __restrict__ text,
                                               char* __restrict__ ws) {
  const int tid = threadIdx.x, lane = tid & 63, wave = tid >> 6;
  const int l15 = lane & 15, quad = lane >> 4;
  const int Nb = blockIdx.x, Mb = blockIdx.y;  // 32 x 200
  const bf16* embB = (const bf16*)(ws + O_EMBB);
  const bf16* WembP = (const bf16*)(ws + O_WEMBP);
  const float* b1p = (const float*)(ws + O_B1P);
  bf16* X1 = (bf16*)(ws + O_X1);

  int m = Mb * 64 + wave * 16 + l15;
  int tcol = m >> 6, n = m & 63;
  int vid = text[n * 200 + tcol];  // row 0 of emb is all-zero (padding)
  const bf16* arow = embB + (size_t)vid * 512 + quad * 8;

  f32x4 acc[4];
#pragma unroll
  for (int nt = 0; nt < 4; ++nt) {
    float b = b1p[Nb * 64 + nt * 16 + l15];
    acc[nt] = (f32x4){b, b, b, b};
  }
  for (int kt = 0; kt < 16; ++kt) {
    bf16x8 af = *(const bf16x8*)(arow + kt * 32);
#pragma unroll
    for (int nt = 0; nt < 4; ++nt) {
      bf16x8 bfr = *(const bf16x8*)(WembP + (size_t)(Nb * 64 + nt * 16 + l15) * 512 +
                                    kt * 32 + quad * 8);
      acc[nt] = MFMA(af, bfr, acc[nt]);
    }
  }
#pragma unroll
  for (int nt = 0; nt < 4; ++nt)
#pragma unroll
    for (int r = 0; r < 4; ++r) {
      int mr = Mb * 64 + wave * 16 + quad * 4 + r;
      X1[(size_t)mr * 2048 + Nb * 64 + nt * 16 + l15] = (bf16)acc[nt][r];
    }
}

// ================= v4: barrier-free per-row persistent loop =================
// Grid 64 x 512. WG b owns batch row n = b for all 200 steps.
// Per step: z1 = X1pre + [ctx|h1]@Wz1^T (MFMA GEMV, x broadcast over M-rows),
// LSTM1 gate; z2 = [h2|h1]@Wz2^T (MFMA GEMV), LSTM2 gate; attention
// (energies from LDS-staged K, softmax, ctx = p@V streamed from L2).
// c1/c2 live in registers (thread u owns unit u); h/x vectors in LDS.
__global__ __launch_bounds__(512, 1) void loop_kernel(const float* __restrict__ values,
                                                      const int* __restrict__ lens,
                                                      char* __restrict__ ws) {
  extern __shared__ __align__(16) char smem[];
  const int n = blockIdx.x, tid = threadIdx.x;
  const int lane = tid & 63, w = tid >> 6;
  const int l15 = lane & 15, quad = lane >> 4;

  const bf16* Wz1p = (const bf16*)(ws + O_WZ1);
  const bf16* Wz2p = (const bf16*)(ws + O_WZ2);
  const float* b2p = (const float*)(ws + O_B2P);
  const uint* keyW = (const uint*)(ws + O_KEYB);   // bf16-pairs as uint
  const uint* valW = (const uint*)(ws + O_VALB);
  const bf16* X1 = (const bf16*)(ws + O_X1);
  bf16* h2ctx = (bf16*)(ws + O_H2CTX);

  uint* kl = (uint*)(smem + LK_K);
  bf16* x1 = (bf16*)(smem + LK_X1);
  bf16* x2 = (bf16*)(smem + LK_X2);
  float* z1 = (float*)(smem + LK_Z1);
  float* z2 = (float*)(smem + LK_Z2);
  float* h2f = (float*)(smem + LK_H2F);
  float* pL = (float*)(smem + LK_P);
  float* cp = (float*)(smem + LK_CP);
  float* red = (float*)(smem + LK_RED);

  const int lenr = lens[n];

  // ---- prologue: stage K[.,n,.] into LDS (pitch 66 uints), init state ----
  for (int i = tid; i < 500 * 64; i += 512) {
    int r = i >> 6, cw = i & 63;
    kl[r * 66 + cw] = keyW[(size_t)(r * 64 + n) * 64 + cw];
  }
  if (tid < 128) x1[tid] = (bf16)values[n * 128 + tid];  // ctx0 = values[0][n]
  x1[128 + tid] = (bf16)0.f;                              // h1 = 0
  if (tid < 128) x2[tid] = (bf16)0.f;                     // h2 = 0
  x2[128 + tid] = (bf16)0.f;
  float c1 = 0.f, c2 = 0.f;  // thread tid owns unit tid (c2: tid<128)
  __syncthreads();

  for (int t = 0; t < 200; ++t) {
    // ================= z1 GEMV (MFMA, 2048 outputs, K=640) =================
    // A = x1 broadcast to all 16 M-rows; B = Wz1p gate rows from global (L2).
    bf16x8 af[20];
#pragma unroll
    for (int kt = 0; kt < 20; ++kt)
      af[kt] = *(const bf16x8*)(smem + LK_X1 + kt * 64 + quad * 16);
    for (int tp = 0; tp < 8; ++tp) {  // 8 tile-pairs per wave: 128 tiles total
      int g0 = (w * 16 + tp * 2) * 16 + l15;
      const bf16* B0 = Wz1p + (size_t)g0 * 640 + quad * 8;
      const bf16* B1 = B0 + 16 * 640;
      f32x4 a0 = {0.f, 0.f, 0.f, 0.f}, a1 = {0.f, 0.f, 0.f, 0.f};
#pragma unroll
      for (int kt = 0; kt < 20; ++kt) {
        a0 = MFMA(af[kt], *(const bf16x8*)(B0 + kt * 32), a0);
        a1 = MFMA(af[kt], *(const bf16x8*)(B1 + kt * 32), a1);
      }
      if (quad == 0) {  // all M-rows identical -> acc[0] is z1[gate]
        z1[g0] = a0[0];
        z1[g0 + 16] = a1[0];
      }
    }
    __syncthreads();
    // ================= LSTM1 gating (thread u = unit u) =================
    {
      float4 zv = *(const float4*)(z1 + 4 * tid);  // (i,f,g,o) of unit tid
      ushort4 xv = *(const ushort4*)(X1 + (size_t)(t * 64 + n) * 2048 + 4 * tid);
      float zi = zv.x + bfu(xv.x);
      float zf = zv.y + bfu(xv.y);
      float zg = zv.z + bfu(xv.z);
      float zo = zv.w + bfu(xv.w);
      c1 = sigf(zf) * c1 + sigf(zi) * tanhf_(zg);
      float h = sigf(zo) * tanhf_(c1);
      bf16 hb = (bf16)h;
      x1[128 + tid] = hb;  // h1 for next step's z1
      x2[128 + tid] = hb;  // h1 for this step's z2
    }
    __syncthreads();
    // ================= z2 GEMV (MFMA, 512 outputs, K=640) =================
#pragma unroll
    for (int kt = 0; kt < 20; ++kt)
      af[kt] = *(const bf16x8*)(smem + LK_X2 + kt * 64 + quad * 16);
    for (int tp = 0; tp < 2; ++tp) {  // 2 tile-pairs per wave: 32 tiles total
      int g0 = (w * 4 + tp * 2) * 16 + l15;
      const bf16* B0 = Wz2p + (size_t)g0 * 640 + quad * 8;
      const bf16* B1 = B0 + 16 * 640;
      f32x4 a0 = {0.f, 0.f, 0.f, 0.f}, a1 = {0.f, 0.f, 0.f, 0.f};
#pragma unroll
      for (int kt = 0; kt < 20; ++kt) {
        a0 = MFMA(af[kt], *(const bf16x8*)(B0 + kt * 32), a0);
        a1 = MFMA(af[kt], *(const bf16x8*)(B1 + kt * 32), a1);
      }
      if (quad == 0) {
        z2[g0] = a0[0];
        z2[g0 + 16] = a1[0];
      }
    }
    __syncthreads();
    // ================= LSTM2 gating (threads 0..127 = unit u) =================
    if (tid < 128) {
      float4 zv = *(const float4*)(z2 + 4 * tid);
      float4 bb = *(const float4*)(b2p + 4 * tid);
      float zi = zv.x + bb.x, zf = zv.y + bb.y, zg = zv.z + bb.z, zo = zv.w + bb.w;
      c2 = sigf(zf) * c2 + sigf(zi) * tanhf_(zg);
      float h = sigf(zo) * tanhf_(c2);
      h2f[tid] = h;            // f32 query for energies
      bf16 hb = (bf16)h;
      x2[tid] = hb;            // h2 for next step's z2
      h2ctx[(size_t)(t * 64 + n) * 256 + tid] = hb;
    }
    __syncthreads();
    // ================= attention =================
    {
      // energies: thread tt computes e[tt] = K[tt,n,:] . h2   (K from LDS)
      float e = -1e30f;
      if (tid < lenr) {
        const uint* kr = kl + tid * 66;
        float s = 0.f;
#pragma unroll 8
        for (int i = 0; i < 32; ++i) {
          uint kx = kr[2 * i], ky = kr[2 * i + 1];
          float4 h4 = *(const float4*)(h2f + 4 * i);  // broadcast
          s += h4.x * bflo(kx) + h4.y * bfhi(kx) + h4.z * bflo(ky) + h4.w * bfhi(ky);
        }
        e = s;
      }
      float wm = wred_max(e);
      if (lane == 0) red[w] = wm;
      __syncthreads();
      float mx = red[0];
#pragma unroll
      for (int i = 1; i < 8; ++i) mx = fmaxf(mx, red[i]);
      float pv = (tid < lenr) ? __expf(e - mx) : 0.f;
      pL[tid] = pv;
      float wsum = wred_sum(pv);
      if (lane == 0) red[8 + w] = wsum;
      __syncthreads();
      float S = red[8];
#pragma unroll
      for (int i = 1; i < 8; ++i) S += red[8 + i];
      float inv = 1.f / S;
      // ctx = p @ V : thread (kq = tid&31 -> k=4kq..4kq+3, c = tid>>5) sums a
      // 32-wide tt-chunk; V streamed from global (L2), coalesced uint2 loads.
      {
        int kq = tid & 31, c = tid >> 5;
        int t0 = c * 32;
        int t1 = (t0 + 32 < lenr) ? (t0 + 32) : lenr;
        float a0 = 0.f, a1 = 0.f, a2 = 0.f, a3 = 0.f;
        for (int tt = t0; tt < t1; ++tt) {
          float pw = pL[tt];  // broadcast (2 addrs per wave)
          const uint* vp = valW + (size_t)(tt * 64 + n) * 64 + 2 * kq;
          uint vx = vp[0], vy = vp[1];
          a0 += pw * bflo(vx);
          a1 += pw * bfhi(vx);
          a2 += pw * bflo(vy);
          a3 += pw * bfhi(vy);
        }
        *(float4*)(cp + c * 128 + 4 * kq) = make_float4(a0, a1, a2, a3);
      }
      __syncthreads();
      if (tid < 128) {
        float s = 0.f;
#pragma unroll
        for (int c = 0; c < 16; ++c) s += cp[c * 128 + tid];
        float cv = s * inv;
        bf16 cb = (bf16)cv;
        x1[tid] = cb;  // ctx for next step's z1
        h2ctx[(size_t)(t * 64 + n) * 256 + 128 + tid] = cb;
      }
    }
    __syncthreads();  // protect x1 / pL / cp / red for next iteration
  }
}

// ========================= K4: output projection ===========================
__global__ __launch_bounds__(256) void k4_gemm(const float* __restrict__ bout,
                                               float* __restrict__ out,
                                               char* __restrict__ ws) {
  const int tid = threadIdx.x, lane = tid & 63, wave = tid >> 6;
  const int l15 = lane & 15, quad = lane >> 4;
  const int Nb = blockIdx.x, Mb = blockIdx.y;  // 63 x 200
  const bf16* A = (const bf16*)(ws + O_H2CTX);
  const bf16* B = (const bf16*)(ws + O_WOUTB);

  int mrow = Mb * 64 + wave * 16 + l15;
  const bf16* arow = A + (size_t)mrow * 256 + quad * 8;

  int vs[8];
  f32x4 acc[8];
#pragma unroll
  for (int nt = 0; nt < 8; ++nt) {
    int v = Nb * 128 + nt * 16 + l15;
    vs[nt] = v < 8000 ? v : 7999;
    float b = (v < 8000) ? bout[v] : 0.f;
    acc[nt] = (f32x4){b, b, b, b};
  }
#pragma unroll
  for (int kt = 0; kt < 8; ++kt) {
    bf16x8 af = *(const bf16x8*)(arow + kt * 32);
#pragma unroll
    for (int nt = 0; nt < 8; ++nt) {
      bf16x8 bfr = *(const bf16x8*)(B + (size_t)vs[nt] * 256 + kt * 32 + quad * 8);
      acc[nt] = MFMA(af, bfr, acc[nt]);
    }
  }
#pragma unroll
  for (int nt = 0; nt < 8; ++nt) {
    int v = Nb * 128 + nt * 16 + l15;
    if (v < 8000) {
#pragma unroll
      for (int r = 0; r < 4; ++r) {
        int mr = Mb * 64 + wave * 16 + quad * 4 + r;
        int n = mr & 63, tt = mr >> 6;
        out[(size_t)(n * 200 + tt) * 8000 + v] = acc[nt][r];
      }
    }
  }
}

// ================================ launch ===================================
extern "C" void kernel_launch(void* const* d_in, const int* in_sizes, int n_in,
                              void* d_out, int out_size, void* d_ws, size_t ws_size,
                              hipStream_t stream) {
  const float* key = (const float*)d_in[0];
  const float* values = (const float*)d_in[1];
  const int* lens = (const int*)d_in[2];
  const int* text = (const int*)d_in[3];
  const float* emb = (const float*)d_in[4];
  const float* Wih1 = (const float*)d_in[5];
  const float* Whh1 = (const float*)d_in[6];
  const float* bih1 = (const float*)d_in[7];
  const float* bhh1 = (const float*)d_in[8];
  const float* Wih2 = (const float*)d_in[9];
  const float* Whh2 = (const float*)d_in[10];
  const float* bih2 = (const float*)d_in[11];
  const float* bhh2 = (const float*)d_in[12];
  const float* Wout = (const float*)d_in[13];
  const float* bout = (const float*)d_in[14];
  float* out = (float*)d_out;
  char* ws = (char*)d_ws;

  // allow >64KB dynamic LDS for the persistent kernel (idempotent)
  hipFuncSetAttribute(reinterpret_cast<const void*>(loop_kernel),
                      hipFuncAttributeMaxDynamicSharedMemorySize, 160 * 1024);

  prep_kernel<<<1024, 256, 0, stream>>>(key, values, emb, Wih1, Whh1, bih1, bhh1,
                                        Wih2, Whh2, bih2, bhh2, Wout, ws);
  k1_gemm<<<dim3(32, 200), 256, 0, stream>>>(text, ws);
  loop_kernel<<<64, 512, LDS2_TOTAL, stream>>>(values, lens, ws);
  k4_gemm<<<dim3(63, 200), 256, 0, stream>>>(bout, out, ws);
}

// Round 5
// 6219.867 us; speedup vs baseline: 4.5717x; 4.5717x over previous
//
#include <hip/hip_runtime.h>
#include <hip/hip_bf16.h>

// ---------------------------------------------------------------------------
// Decoder: 200-step attention LSTM decoder.  v5: LAUNCH-SYNCHRONIZED.
//   prep_kernel : convert/permute weights & KV to bf16, zero h-state
//   k1_gemm     : X1pre[t,n,2048] = emb[text] @ Wih1_emb^T + bias       (MFMA)
//   phaseA x200 : ctx combine + z1 GEMM slice + LSTM1 gating  (256 WGs)
//   phaseB x200 : z2 GEMM slice + LSTM2 gating                (32 WGs)
//   phaseC x200 : attention energies/softmax/ctx partials     (256 WGs)
//   ctx_final   : finalize ctx(199) into h2ctx
//   k4_gemm     : out[n,l,:] = [h2|ctx] @ W_out^T + b_out             (MFMA)
//
// Rationale (rounds 0-4): the persistent-kernel grid barrier cost ~37us per
// phase (600 phases = entire runtime) and two attempts at relaxed-poll
// barriers died unverifiable; the barrier-free per-row design (v4) is
// structurally bound by per-CU weight streaming (6.8 GB/dispatch fetch).
// v5 keeps the VERIFIED round-0 weight-stationary phase bodies and uses
// kernel boundaries as the grid barrier: hardware-guaranteed sync +
// coherence, no atomics, no polling, replay-safe. LDS is re-staged per
// launch (20-66 KB from L2/L3, <1us); c1/c2 persist in global scratch
// (dead embB region; t==0 ignores stale contents).
// Workspace requirement: ~93.3 MB (unchanged layout).
// ---------------------------------------------------------------------------

typedef __bf16 bf16;
typedef __attribute__((ext_vector_type(8))) __bf16 bf16x8;
typedef __attribute__((ext_vector_type(4))) float f32x4;
typedef unsigned int uint;

#define MFMA(a, b, c) __builtin_amdgcn_mfma_f32_16x16x32_bf16((a), (b), (c), 0, 0, 0)

// ---- workspace byte offsets (all 256-aligned) ----
#define O_X1     0UL          // X1pre bf16 [200][64][2048]          52,428,800
#define O_EMBB   52428800UL   // emb bf16 [8000][512] (k1 input; loop reuses as c-state)
#define O_C1     52428800UL   //   c1 fp32 [64][512] = 131,072 B (valid only during loop)
#define O_C2     52559872UL   //   c2 fp32 [64][128] =  32,768 B
#define O_WEMBP  60620800UL   // Wih1 embed-part, permuted rows, bf16 [2048][512]
#define O_WZ1    62717952UL   // [Wih1_ctx | Whh1] permuted, bf16 [2048][640]
#define O_WZ2    65339392UL   // [Whh2 | Wih2] permuted, bf16 [512][640]
#define O_B1P    65994752UL   // b_ih1+b_hh1 permuted fp32 [2048]
#define O_B2P    66002944UL   // b_ih2+b_hh2 permuted fp32 [512]
#define O_WOUTB  66004992UL   // W_out bf16 [8000][256]
#define O_KEYB   70100992UL   // key bf16 [500][64][128]
#define O_VALB   78292992UL   // values bf16 [500][64][128]
#define O_H1     86484992UL   // h1 state bf16 [2][64][512]
#define O_H2     86616064UL   // h2 state bf16 [2][64][128]
#define O_PART   86648832UL   // attn partials [64][4][272B]: m,s fp32 + 128 bf16
#define O_H2CTX  86718464UL   // [h2|ctx] bf16 [200][64][256]

// ---- per-phase LDS offsets (dynamic shared) ----
#define AA_WA   0        // A-weight slice: 16 rows x 640, pitch 648 halves (20736B)
#define AA_CTX  20736    // ctx stage: 32 x 128, pitch 136 halves (8704B)
#define AA_ZS   29440    // z scratch: [4 waves][32 m][33] fp32 (16896B)
#define A_LDS   46336

#define BB_WB   0        // B-weight slice: 32 rows x 640, pitch 648 (41472B)
#define BB_ZS   41472    // z scratch (16896B)
#define B_LDS   58368

#define CC_KEY  0        // key chunk: 125 x 128, pitch 132 halves (33000B)
#define CC_VAL  33000    // val chunk: same
#define CC_EL   66000    // energies [128] fp32
#define CC_PL   66512    // probs [128] fp32
#define CC_H2F  67024    // h2 row [128] fp32
#define CC_RED  67536    // reduction scratch
#define C_LDS   67600

__device__ inline float sigf(float x) { return 1.f / (1.f + __expf(-x)); }
__device__ inline float tanhf_(float x) { float e = __expf(2.f * x); return 1.f - 2.f / (e + 1.f); }
__device__ inline float bflo(uint u) { union { uint u; float f; } c; c.u = u << 16; return c.f; }
__device__ inline float bfhi(uint u) { union { uint u; float f; } c; c.u = u & 0xffff0000u; return c.f; }
__device__ inline float wred_max(float v) {
#pragma unroll
  for (int m = 32; m; m >>= 1) v = fmaxf(v, __shfl_xor(v, m, 64));
  return v;
}
__device__ inline float wred_sum(float v) {
#pragma unroll
  for (int m = 32; m; m >>= 1) v += __shfl_xor(v, m, 64);
  return v;
}

// =============================== prep ======================================
__global__ __launch_bounds__(256) void prep_kernel(
    const float* __restrict__ key, const float* __restrict__ values,
    const float* __restrict__ emb, const float* __restrict__ Wih1,
    const float* __restrict__ Whh1, const float* __restrict__ bih1,
    const float* __restrict__ bhh1, const float* __restrict__ Wih2,
    const float* __restrict__ Whh2, const float* __restrict__ bih2,
    const float* __restrict__ bhh2, const float* __restrict__ Wout,
    char* __restrict__ ws) {
  long g = (long)blockIdx.x * 256 + threadIdx.x;
  long str = (long)gridDim.x * 256;
  bf16* embB = (bf16*)(ws + O_EMBB);
  bf16* WembP = (bf16*)(ws + O_WEMBP);
  bf16* Wz1p = (bf16*)(ws + O_WZ1);
  bf16* Wz2p = (bf16*)(ws + O_WZ2);
  float* b1p = (float*)(ws + O_B1P);
  float* b2p = (float*)(ws + O_B2P);
  bf16* WoutB = (bf16*)(ws + O_WOUTB);
  bf16* keyB = (bf16*)(ws + O_KEYB);
  bf16* valB = (bf16*)(ws + O_VALB);

  for (long i = g; i < 8000L * 512; i += str) embB[i] = (bf16)emb[i];
  for (long i = g; i < 2048L * 512; i += str) {
    long gg = i >> 9, k = i & 511;
    long pg = (gg & 3) * 512 + (gg >> 2);
    WembP[i] = (bf16)Wih1[pg * 640 + k];
  }
  for (long i = g; i < 2048L * 640; i += str) {
    long gg = i / 640, k = i - gg * 640;
    long pg = (gg & 3) * 512 + (gg >> 2);
    float v = (k < 128) ? Wih1[pg * 640 + 512 + k] : Whh1[pg * 512 + (k - 128)];
    Wz1p[i] = (bf16)v;
  }
  for (long i = g; i < 512L * 640; i += str) {
    long gg = i / 640, k = i - gg * 640;
    long pg = (gg & 3) * 128 + (gg >> 2);
    float v = (k < 128) ? Whh2[pg * 128 + k] : Wih2[pg * 512 + (k - 128)];
    Wz2p[i] = (bf16)v;
  }
  for (long i = g; i < 2048; i += str) {
    long pg = (i & 3) * 512 + (i >> 2);
    b1p[i] = bih1[pg] + bhh1[pg];
  }
  for (long i = g; i < 512; i += str) {
    long pg = (i & 3) * 128 + (i >> 2);
    b2p[i] = bih2[pg] + bhh2[pg];
  }
  for (long i = g; i < 8000L * 256; i += str) WoutB[i] = (bf16)Wout[i];
  for (long i = g; i < 500L * 64 * 128; i += str) {
    keyB[i] = (bf16)key[i];
    valB[i] = (bf16)values[i];
  }
  // zero h1/h2 state (163840 B) — phaseA/B at t==0 read slot 0
  uint* z = (uint*)(ws + O_H1);
  for (long i = g; i < 40960; i += str) z[i] = 0u;
}

// ========================= K1: embedding pre-GEMM ==========================
// X1pre[m=t*64+n][g~] = sum_k emb[text[n][t]][k] * WembP[g~][k] + b1p[g~]
__global__ __launch_bounds__(256) void k1_gemm(const int* __restrict__ text,
                                               char* __restrict__ ws) {
  const int tid = threadIdx.x, lane = tid & 63, wave = tid >> 6;
  const int l15 = lane & 15, quad = lane >> 4;
  const int Nb = blockIdx.x, Mb = blockIdx.y;  // 32 x 200
  const bf16* embB = (const bf16*)(ws + O_EMBB);
  const bf16* WembP = (const bf16*)(ws + O_WEMBP);
  const float* b1p = (const float*)(ws + O_B1P);
  bf16* X1 = (bf16*)(ws + O_X1);

  int m = Mb * 64 + wave * 16 + l15;
  int tcol = m >> 6, n = m & 63;
  int vid = text[n * 200 + tcol];  // row 0 of emb is all-zero (padding)
  const bf16* arow = embB + (size_t)vid * 512 + quad * 8;

  f32x4 acc[4];
#pragma unroll
  for (int nt = 0; nt < 4; ++nt) {
    float b = b1p[Nb * 64 + nt * 16 + l15];
    acc[nt] = (f32x4){b, b, b, b};
  }
  for (int kt = 0; kt < 16; ++kt) {
    bf16x8 af = *(const bf16x8*)(arow + kt * 32);
#pragma unroll
    for (int nt = 0; nt < 4; ++nt) {
      bf16x8 bfr = *(const bf16x8*)(WembP + (size_t)(Nb * 64 + nt * 16 + l15) * 512 +
                                    kt * 32 + quad * 8);
      acc[nt] = MFMA(af, bfr, acc[nt]);
    }
  }
#pragma unroll
  for (int nt = 0; nt < 4; ++nt)
#pragma unroll
    for (int r = 0; r < 4; ++r) {
      int mr = Mb * 64 + wave * 16 + quad * 4 + r;
      X1[(size_t)mr * 2048 + Nb * 64 + nt * 16 + l15] = (bf16)acc[nt][r];
    }
}

// ================== shared helper: combine attention partials ==============
__device__ inline void combine_ctx(int t, int nA0, int ga, int tid,
                                   bf16* __restrict__ ctx_base, const char* __restrict__ part,
                                   bf16* __restrict__ h2ctx, bool wlds) {
  int m = tid >> 3, kk = tid & 7;
  const char* pb = part + (size_t)(nA0 + m) * 4 * 272;
  float mc0 = ((const float*)(pb))[0], sc0 = ((const float*)(pb))[1];
  float mc1 = ((const float*)(pb + 272))[0], sc1 = ((const float*)(pb + 272))[1];
  float mc2 = ((const float*)(pb + 544))[0], sc2 = ((const float*)(pb + 544))[1];
  float mc3 = ((const float*)(pb + 816))[0], sc3 = ((const float*)(pb + 816))[1];
  float M = fmaxf(fmaxf(mc0, mc1), fmaxf(mc2, mc3));
  float w0 = __expf(mc0 - M), w1 = __expf(mc1 - M);
  float w2 = __expf(mc2 - M), w3 = __expf(mc3 - M);
  float S = sc0 * w0 + sc1 * w1 + sc2 * w2 + sc3 * w3;
  float inv = 1.f / S;
  const bf16* x0 = (const bf16*)(pb + 8);
  const bf16* x1 = (const bf16*)(pb + 280);
  const bf16* x2 = (const bf16*)(pb + 552);
  const bf16* x3 = (const bf16*)(pb + 824);
#pragma unroll
  for (int i = 0; i < 16; ++i) {
    int k = kk * 16 + i;
    float v = w0 * (float)x0[k] + w1 * (float)x1[k] + w2 * (float)x2[k] + w3 * (float)x3[k];
    bf16 hv = (bf16)(v * inv);
    if (wlds) ctx_base[m * 136 + k] = hv;
    if (ga == 0) h2ctx[(size_t)((t - 1) * 64 + nA0 + m) * 256 + 128 + k] = hv;
  }
}

// ===================== phase A: ctx combine + LSTM1 ========================
// 256 WGs: ra=bid&1 (row half), ga=bid>>1 (16 z~ gate rows)
__global__ __launch_bounds__(256) void phaseA(const float* __restrict__ values,
                                              int t, char* __restrict__ ws) {
  extern __shared__ __align__(16) char smem[];
  const int bid = blockIdx.x, tid = threadIdx.x;
  const int lane = tid & 63, wave = tid >> 6;
  const int l15 = lane & 15, quad = lane >> 4;
  const int ra = bid & 1, ga = bid >> 1;
  const int nA0 = 32 * ra;
  const int p = t & 1;

  const bf16* Wz1p = (const bf16*)(ws + O_WZ1);
  const bf16* X1 = (const bf16*)(ws + O_X1);
  bf16* h1b = (bf16*)(ws + O_H1);
  char* part = ws + O_PART;
  bf16* h2ctx = (bf16*)(ws + O_H2CTX);
  float* c1g = (float*)(ws + O_C1);

  // stage A-weight slice (16 rows x 1280B) from L2
  for (int i = tid; i < 16 * 80; i += 256) {
    int r = i / 80, c = i % 80;
    *(uint4*)(smem + AA_WA + r * 1296 + c * 16) =
        *(const uint4*)((const char*)Wz1p + (size_t)(16 * ga + r) * 1280 + c * 16);
  }
  // ctx(t-1) into LDS
  if (t == 0) {
    int m = tid >> 3, kk = tid & 7;
    bf16* ctxL = (bf16*)(smem + AA_CTX) + m * 136;
#pragma unroll
    for (int i = 0; i < 16; ++i) {
      int k = kk * 16 + i;
      ctxL[k] = (bf16)values[(nA0 + m) * 128 + k];
    }
  } else {
    combine_ctx(t, nA0, ga, tid, (bf16*)(smem + AA_CTX), part, h2ctx, true);
  }
  __syncthreads();
  // z1 = [ctx | h1prev] @ slice(Wz1p)^T  (K split over 4 waves)
  {
    f32x4 acc0 = {0, 0, 0, 0}, acc1 = {0, 0, 0, 0};
    const bf16* h1p = h1b + p * 32768;
#pragma unroll
    for (int q = 0; q < 5; ++q) {
      int kt = wave * 5 + q;
      bf16x8 bfr = *(const bf16x8*)(smem + AA_WA + l15 * 1296 + (kt * 32 + quad * 8) * 2);
      bf16x8 a0, a1;
      if (kt < 4) {
        a0 = *(const bf16x8*)(smem + AA_CTX + l15 * 272 + (kt * 32 + quad * 8) * 2);
        a1 = *(const bf16x8*)(smem + AA_CTX + (16 + l15) * 272 + (kt * 32 + quad * 8) * 2);
      } else {
        const bf16* base = h1p + (kt - 4) * 32 + quad * 8;
        a0 = *(const bf16x8*)(base + (size_t)(nA0 + l15) * 512);
        a1 = *(const bf16x8*)(base + (size_t)(nA0 + 16 + l15) * 512);
      }
      acc0 = MFMA(a0, bfr, acc0);
      acc1 = MFMA(a1, bfr, acc1);
    }
    float* zs = (float*)(smem + AA_ZS) + wave * 1056;
#pragma unroll
    for (int r = 0; r < 4; ++r) {
      zs[(quad * 4 + r) * 33 + l15] = acc0[r];
      zs[(16 + quad * 4 + r) * 33 + l15] = acc1[r];
    }
  }
  __syncthreads();
  // gating -> h1(t), c1
  if (tid < 128) {
    int m = tid >> 2, j = tid & 3;
    float zi = 0, zf = 0, zg = 0, zo = 0;
    const float* zr = (const float*)(smem + AA_ZS);
#pragma unroll
    for (int w = 0; w < 4; ++w) {
      const float* q_ = zr + w * 1056 + m * 33 + 4 * j;
      zi += q_[0]; zf += q_[1]; zg += q_[2]; zo += q_[3];
    }
    const bf16* xp = X1 + (size_t)(t * 64 + nA0 + m) * 2048 + ga * 16 + 4 * j;
    zi += (float)xp[0]; zf += (float)xp[1]; zg += (float)xp[2]; zo += (float)xp[3];
    int ci = (nA0 + m) * 512 + ga * 4 + j;
    float cprev = (t == 0) ? 0.f : c1g[ci];
    float c = sigf(zf) * cprev + sigf(zi) * tanhf_(zg);
    float h = sigf(zo) * tanhf_(c);
    c1g[ci] = c;
    h1b[(p ^ 1) * 32768 + (size_t)(nA0 + m) * 512 + ga * 4 + j] = (bf16)h;
  }
}

// =========================== phase B: LSTM2 ================================
// 32 WGs: hb=bid>>1 (32 z~ rows), nB0=32*(bid&1)
__global__ __launch_bounds__(256) void phaseB(int t, char* __restrict__ ws) {
  extern __shared__ __align__(16) char smem[];
  const int bid = blockIdx.x, tid = threadIdx.x;
  const int lane = tid & 63, wave = tid >> 6;
  const int l15 = lane & 15, quad = lane >> 4;
  const int hb = bid >> 1;
  const int nB0 = 32 * (bid & 1);
  const int p = t & 1;

  const bf16* Wz2p = (const bf16*)(ws + O_WZ2);
  const float* b2p = (const float*)(ws + O_B2P);
  bf16* h1b = (bf16*)(ws + O_H1);
  bf16* h2b = (bf16*)(ws + O_H2);
  bf16* h2ctx = (bf16*)(ws + O_H2CTX);
  float* c2g = (float*)(ws + O_C2);

  for (int i = tid; i < 32 * 80; i += 256) {
    int r = i / 80, c = i % 80;
    *(uint4*)(smem + BB_WB + r * 1296 + c * 16) =
        *(const uint4*)((const char*)Wz2p + (size_t)(32 * hb + r) * 1280 + c * 16);
  }
  __syncthreads();
  {
    f32x4 a00 = {0, 0, 0, 0}, a01 = {0, 0, 0, 0}, a10 = {0, 0, 0, 0}, a11 = {0, 0, 0, 0};
    const bf16* h2p = h2b + p * 8192;
    const bf16* h1n = h1b + (p ^ 1) * 32768;
#pragma unroll
    for (int q = 0; q < 5; ++q) {
      int kt = wave * 5 + q;
      bf16x8 b0 = *(const bf16x8*)(smem + BB_WB + l15 * 1296 + (kt * 32 + quad * 8) * 2);
      bf16x8 b1 = *(const bf16x8*)(smem + BB_WB + (16 + l15) * 1296 + (kt * 32 + quad * 8) * 2);
      bf16x8 a0, a1;
      if (kt < 4) {
        const bf16* base = h2p + kt * 32 + quad * 8;
        a0 = *(const bf16x8*)(base + (size_t)(nB0 + l15) * 128);
        a1 = *(const bf16x8*)(base + (size_t)(nB0 + 16 + l15) * 128);
      } else {
        const bf16* base = h1n + (kt - 4) * 32 + quad * 8;
        a0 = *(const bf16x8*)(base + (size_t)(nB0 + l15) * 512);
        a1 = *(const bf16x8*)(base + (size_t)(nB0 + 16 + l15) * 512);
      }
      a00 = MFMA(a0, b0, a00); a01 = MFMA(a0, b1, a01);
      a10 = MFMA(a1, b0, a10); a11 = MFMA(a1, b1, a11);
    }
    float* zs = (float*)(smem + BB_ZS) + wave * 1056;
#pragma unroll
    for (int r = 0; r < 4; ++r) {
      zs[(quad * 4 + r) * 33 + l15] = a00[r];
      zs[(quad * 4 + r) * 33 + 16 + l15] = a01[r];
      zs[(16 + quad * 4 + r) * 33 + l15] = a10[r];
      zs[(16 + quad * 4 + r) * 33 + 16 + l15] = a11[r];
    }
  }
  __syncthreads();
  {
    int m = tid >> 3, jj = tid & 7;
    float zi = 0, zf = 0, zg = 0, zo = 0;
    const float* zr = (const float*)(smem + BB_ZS);
#pragma unroll
    for (int w = 0; w < 4; ++w) {
      const float* q_ = zr + w * 1056 + m * 33 + 4 * jj;
      zi += q_[0]; zf += q_[1]; zg += q_[2]; zo += q_[3];
    }
    const float* bb = b2p + 32 * hb + 4 * jj;
    zi += bb[0]; zf += bb[1]; zg += bb[2]; zo += bb[3];
    int ci = (nB0 + m) * 128 + 8 * hb + jj;
    float cprev = (t == 0) ? 0.f : c2g[ci];
    float c = sigf(zf) * cprev + sigf(zi) * tanhf_(zg);
    float h = sigf(zo) * tanhf_(c);
    c2g[ci] = c;
    bf16 hv = (bf16)h;
    h2b[(p ^ 1) * 8192 + (size_t)(nB0 + m) * 128 + 8 * hb + jj] = hv;
    h2ctx[(size_t)(t * 64 + nB0 + m) * 256 + 8 * hb + jj] = hv;
  }
}

// ========================= phase C: attention ==============================
// 256 WGs: nc=bid>>2 (row), cc=bid&3 (T-chunk of 125)
__global__ __launch_bounds__(256) void phaseC(const int* __restrict__ lens,
                                              int t, char* __restrict__ ws) {
  extern __shared__ __align__(16) char smem[];
  const int bid = blockIdx.x, tid = threadIdx.x;
  const int lane = tid & 63, w = tid >> 6;
  const int nc = bid >> 2, cc = bid & 3;
  const int p = t & 1;

  const bf16* keyB = (const bf16*)(ws + O_KEYB);
  const bf16* valB = (const bf16*)(ws + O_VALB);
  const bf16* h2b = (const bf16*)(ws + O_H2);
  char* part = ws + O_PART;

  float* eL = (float*)(smem + CC_EL);
  float* pL = (float*)(smem + CC_PL);
  float* h2f = (float*)(smem + CC_H2F);
  float* red = (float*)(smem + CC_RED);

  // stage K/V chunk: 125 rows x 256B each
  for (int i = tid; i < 125 * 32; i += 256) {
    int r = i >> 5, c = i & 31;
    size_t src = ((size_t)(cc * 125 + r) * 64 + nc) * 256 + c * 8;
    *(uint2*)(smem + CC_KEY + r * 264 + c * 8) = *(const uint2*)((const char*)keyB + src);
    *(uint2*)(smem + CC_VAL + r * 264 + c * 8) = *(const uint2*)((const char*)valB + src);
  }
  if (tid < 128) h2f[tid] = (float)h2b[(p ^ 1) * 8192 + (size_t)nc * 128 + tid];
  const int lenr = lens[nc];
  __syncthreads();

  if (tid < 125) {
    int gt = cc * 125 + tid;
    float e = -1e30f;
    if (gt < lenr) {
      const uint* kr = (const uint*)(smem + CC_KEY + tid * 264);
      float s = 0.f;
#pragma unroll 8
      for (int k2 = 0; k2 < 64; ++k2) {
        uint u = kr[k2];
        s += h2f[2 * k2] * bflo(u) + h2f[2 * k2 + 1] * bfhi(u);
      }
      e = s;
    }
    eL[tid] = e;
  } else if (tid < 128) {
    eL[tid] = -1e30f;
  }
  __syncthreads();
  if (tid < 64) {
    float v = fmaxf(eL[tid], eL[tid + 64]);
    v = wred_max(v);
    if (tid == 0) red[0] = v;
  }
  __syncthreads();
  float mC = red[0];
  if (tid < 128) {
    float pv = 0.f;
    if (tid < 125 && (cc * 125 + tid) < lenr) pv = __expf(eL[tid] - mC);
    pL[tid] = pv;
  }
  __syncthreads();
  if (tid < 64) {
    float v = pL[tid] + pL[tid + 64];
    v = wred_sum(v);
    if (tid == 0) red[1] = v;
  }
  __syncthreads();
  {
    char* pbase = part + (size_t)(nc * 4 + cc) * 272;
    if (tid == 0) {
      ((float*)pbase)[0] = mC;
      ((float*)pbase)[1] = red[1];
    }
    if (tid < 64) {
      const char* vbase = smem + CC_VAL + tid * 4;
      float a0 = 0.f, a1 = 0.f;
      for (int tt = 0; tt < 125; ++tt) {
        float pv = pL[tt];
        uint u = *(const uint*)(vbase + tt * 264);
        a0 += pv * bflo(u);
        a1 += pv * bfhi(u);
      }
      bf16* dst = (bf16*)(pbase + 8);
      dst[2 * tid] = (bf16)a0;
      dst[2 * tid + 1] = (bf16)a1;
    }
  }
}

// ================== ctx_final: finalize ctx(199) ===========================
__global__ __launch_bounds__(256) void ctx_final(char* __restrict__ ws) {
  const int nA0 = 32 * blockIdx.x, tid = threadIdx.x;
  combine_ctx(200, nA0, 0, tid, nullptr, ws + O_PART, (bf16*)(ws + O_H2CTX), false);
}

// ========================= K4: output projection ===========================
__global__ __launch_bounds__(256) void k4_gemm(const float* __restrict__ bout,
                                               float* __restrict__ out,
                                               char* __restrict__ ws) {
  const int tid = threadIdx.x, lane = tid & 63, wave = tid >> 6;
  const int l15 = lane & 15, quad = lane >> 4;
  const int Nb = blockIdx.x, Mb = blockIdx.y;  // 63 x 200
  const bf16* A = (const bf16*)(ws + O_H2CTX);
  const bf16* B = (const bf16*)(ws + O_WOUTB);

  int mrow = Mb * 64 + wave * 16 + l15;
  const bf16* arow = A + (size_t)mrow * 256 + quad * 8;

  int vs[8];
  f32x4 acc[8];
#pragma unroll
  for (int nt = 0; nt < 8; ++nt) {
    int v = Nb * 128 + nt * 16 + l15;
    vs[nt] = v < 8000 ? v : 7999;
    float b = (v < 8000) ? bout[v] : 0.f;
    acc[nt] = (f32x4){b, b, b, b};
  }
#pragma unroll
  for (int kt = 0; kt < 8; ++kt) {
    bf16x8 af = *(const bf16x8*)(arow + kt * 32);
#pragma unroll
    for (int nt = 0; nt < 8; ++nt) {
      bf16x8 bfr = *(const bf16x8*)(B + (size_t)vs[nt] * 256 + kt * 32 + quad * 8);
      acc[nt] = MFMA(af, bfr, acc[nt]);
    }
  }
#pragma unroll
  for (int nt = 0; nt < 8; ++nt) {
    int v = Nb * 128 + nt * 16 + l15;
    if (v < 8000) {
#pragma unroll
      for (int r = 0; r < 4; ++r) {
        int mr = Mb * 64 + wave * 16 + quad * 4 + r;
        int n = mr & 63, tt = mr >> 6;
        out[(size_t)(n * 200 + tt) * 8000 + v] = acc[nt][r];
      }
    }
  }
}

// ================================ launch ===================================
extern "C" void kernel_launch(void* const* d_in, const int* in_sizes, int n_in,
                              void* d_out, int out_size, void* d_ws, size_t ws_size,
                              hipStream_t stream) {
  const float* key = (const float*)d_in[0];
  const float* values = (const float*)d_in[1];
  const int* lens = (const int*)d_in[2];
  const int* text = (const int*)d_in[3];
  const float* emb = (const float*)d_in[4];
  const float* Wih1 = (const float*)d_in[5];
  const float* Whh1 = (const float*)d_in[6];
  const float* bih1 = (const float*)d_in[7];
  const float* bhh1 = (const float*)d_in[8];
  const float* Wih2 = (const float*)d_in[9];
  const float* Whh2 = (const float*)d_in[10];
  const float* bih2 = (const float*)d_in[11];
  const float* bhh2 = (const float*)d_in[12];
  const float* Wout = (const float*)d_in[13];
  const float* bout = (const float*)d_in[14];
  float* out = (float*)d_out;
  char* ws = (char*)d_ws;

  // phaseC uses 67.6 KB dynamic LDS (>64KB default cap) — idempotent
  hipFuncSetAttribute(reinterpret_cast<const void*>(phaseC),
                      hipFuncAttributeMaxDynamicSharedMemorySize, 160 * 1024);

  prep_kernel<<<1024, 256, 0, stream>>>(key, values, emb, Wih1, Whh1, bih1, bhh1,
                                        Wih2, Whh2, bih2, bhh2, Wout, ws);
  k1_gemm<<<dim3(32, 200), 256, 0, stream>>>(text, ws);
  for (int t = 0; t < 200; ++t) {
    phaseA<<<256, 256, A_LDS, stream>>>(values, t, ws);
    phaseB<<<32, 256, B_LDS, stream>>>(t, ws);
    phaseC<<<256, 256, C_LDS, stream>>>(lens, t, ws);
  }
  ctx_final<<<2, 256, 0, stream>>>(ws);
  k4_gemm<<<dim3(63, 200), 256, 0, stream>>>(bout, out, ws);
}